// Round 5
// baseline (380.911 us; speedup 1.0000x reference)
//
#include <hip/hip_runtime.h>
#include <stdint.h>

// Problem constants (B=1)
#define L_SEQ 2048
#define DMODEL 1024
#define DI_DIM 2048
#define NSSM 16
#define NPROJ 2080        // DI + 2N
#define NCHUNK 64
#define LCHUNK 32         // NCHUNK*LCHUNK == L_SEQ

typedef __attribute__((ext_vector_type(8))) short bf16x8;
typedef __attribute__((ext_vector_type(4))) float f32x4;

__device__ __forceinline__ float bf2f(unsigned short u) {
  union { uint32_t u; float f; } v; v.u = (uint32_t)u << 16; return v.f;
}
__device__ __forceinline__ unsigned short f2bf(float f) {
  union { float f; uint32_t u; } v; v.f = f;
  uint32_t u = v.u;
  return (unsigned short)((u + 0x7fffu + ((u >> 16) & 1u)) >> 16);
}
__device__ __forceinline__ void async16(const void* g, void* l) {
  __builtin_amdgcn_global_load_lds(
      (__attribute__((address_space(1))) void*)(g),
      (__attribute__((address_space(3))) void*)(l), 16, 0, 0);
}

// ---------------- fused f32 -> bf16 converts (x, W_in, W_x) ----------------
#define CVT_N1 524288                    // x:    2048*1024/4
#define CVT_N2 (CVT_N1 + 1048576)        // W_in: 4096*1024/4
#define CVT_N3 (CVT_N2 + 1064960)        // W_x:  2080*2048/4
__global__ void k_convert3(const float* __restrict__ x, const float* __restrict__ win,
                           const float* __restrict__ wx, unsigned short* __restrict__ xb,
                           unsigned short* __restrict__ winb, unsigned short* __restrict__ wxb) {
  int i = blockIdx.x * 256 + threadIdx.x;
  const float4* src; unsigned short* dst; int j;
  if (i < CVT_N1)      { src = (const float4*)x;   dst = xb;   j = i; }
  else if (i < CVT_N2) { src = (const float4*)win; dst = winb; j = i - CVT_N1; }
  else if (i < CVT_N3) { src = (const float4*)wx;  dst = wxb;  j = i - CVT_N2; }
  else return;
  float4 v = src[j];
  ushort4 o;
  o.x = f2bf(v.x); o.y = f2bf(v.y); o.z = f2bf(v.z); o.w = f2bf(v.w);
  ((ushort4*)dst)[j] = o;
}

__global__ void k_f32_to_bf16(const float* __restrict__ in,
                              unsigned short* __restrict__ out, int n4) {
  int i = blockIdx.x * blockDim.x + threadIdx.x;
  if (i < n4) {
    const float4 v = ((const float4*)in)[i];
    ushort4 o;
    o.x = f2bf(v.x); o.y = f2bf(v.y); o.z = f2bf(v.z); o.w = f2bf(v.w);
    ((ushort4*)out)[i] = o;
  }
}

// ---------------- bf16 N-T GEMM: C[M,N] (+)= A[M,K] * B[N,K]^T + bias ----------------
// m97-style 128x128 tile, BK=32, 4 waves x (4x4) 16x16x32 MFMA, async LDS staging.
// Split-K via gridDim.z: block z handles K-range [z*K/S, (z+1)*K/S).
// ATOMIC=true: f32 atomicAdd epilogue (C must be zeroed); bias added by z==0 splits.
template <typename OutT, bool ATOMIC>
__global__ __launch_bounds__(256) void k_gemm_bt(
    const unsigned short* __restrict__ A, const unsigned short* __restrict__ B,
    const float* __restrict__ bias, OutT* __restrict__ C,
    int M, int N, int K) {
  __shared__ unsigned short As[128 * 32];
  __shared__ unsigned short Bs[128 * 32];
  const int tid = threadIdx.x;
  const int wave = tid >> 6;
  const int lane = tid & 63;
  const int m0 = blockIdx.y * 128;
  const int n0 = blockIdx.x * 128;
  const int kLen = K / gridDim.z;
  const int kLo = blockIdx.z * kLen;

  const int srow = wave * 32 + (lane >> 2);
  const int scol = (lane & 3) * 8;
  int ar0 = m0 + srow;      if (ar0 > M - 1) ar0 = M - 1;
  int ar1 = m0 + srow + 16; if (ar1 > M - 1) ar1 = M - 1;
  int br0 = n0 + srow;      if (br0 > N - 1) br0 = N - 1;
  int br1 = n0 + srow + 16; if (br1 > N - 1) br1 = N - 1;
  const unsigned short* ap0 = A + (size_t)ar0 * K + scol + kLo;
  const unsigned short* ap1 = A + (size_t)ar1 * K + scol + kLo;
  const unsigned short* bp0 = B + (size_t)br0 * K + scol + kLo;
  const unsigned short* bp1 = B + (size_t)br1 * K + scol + kLo;
  unsigned short* as0 = &As[(wave * 32) * 32];
  unsigned short* as1 = &As[(wave * 32 + 16) * 32];
  unsigned short* bs0 = &Bs[(wave * 32) * 32];
  unsigned short* bs1 = &Bs[(wave * 32 + 16) * 32];

  const int wm = wave & 1;
  const int wn = wave >> 1;
  const int fr = lane & 15;
  const int fk = (lane >> 4) * 8;

  f32x4 acc[4][4];
#pragma unroll
  for (int i = 0; i < 4; i++)
#pragma unroll
    for (int j = 0; j < 4; j++) acc[i][j] = (f32x4){0.f, 0.f, 0.f, 0.f};

  for (int kt = 0; kt < kLen; kt += 32) {
    async16(ap0 + kt, as0);
    async16(ap1 + kt, as1);
    async16(bp0 + kt, bs0);
    async16(bp1 + kt, bs1);
    __syncthreads();
    bf16x8 af[4], bfv[4];
#pragma unroll
    for (int i = 0; i < 4; i++)
      af[i] = *(const bf16x8*)&As[(wm * 64 + i * 16 + fr) * 32 + fk];
#pragma unroll
    for (int j = 0; j < 4; j++)
      bfv[j] = *(const bf16x8*)&Bs[(wn * 64 + j * 16 + fr) * 32 + fk];
#pragma unroll
    for (int i = 0; i < 4; i++)
#pragma unroll
      for (int j = 0; j < 4; j++)
        acc[i][j] = __builtin_amdgcn_mfma_f32_16x16x32_bf16(af[i], bfv[j], acc[i][j], 0, 0, 0);
    __syncthreads();
  }

  // epilogue: C/D layout col=lane&15, row=(lane>>4)*4+reg (verified mapping)
  const float bscale = (blockIdx.z == 0) ? 1.f : 0.f;
#pragma unroll
  for (int j = 0; j < 4; j++) {
    int col = n0 + wn * 64 + j * 16 + fr;
    if (col < N) {
      float bv = bias[col] * bscale;
#pragma unroll
      for (int i = 0; i < 4; i++) {
        int rbase = m0 + wm * 64 + i * 16 + (lane >> 4) * 4;
#pragma unroll
        for (int r = 0; r < 4; r++) {
          float v = acc[i][j][r] + bv;
          if constexpr (ATOMIC) {
            atomicAdd((float*)&C[(size_t)(rbase + r) * N + col], v);
          } else if constexpr (sizeof(OutT) == 2) {
            C[(size_t)(rbase + r) * N + col] = (OutT)f2bf(v);
          } else {
            C[(size_t)(rbase + r) * N + col] = (OutT)v;
          }
        }
      }
    }
  }
}

// ---------------- depthwise causal conv (K=4) + bias + SiLU ----------------
__global__ void k_conv_silu(const unsigned short* __restrict__ xr,
                            const float* __restrict__ Wc,
                            const float* __restrict__ bc,
                            unsigned short* __restrict__ xcb) {
  int idx = blockIdx.x * blockDim.x + threadIdx.x;
  if (idx >= L_SEQ * DI_DIM) return;
  int t = idx >> 11;
  int d = idx & (DI_DIM - 1);
  float acc = bc[d];
  const float* wd = Wc + d * 4;
  if (t >= 3) acc += bf2f(xr[(size_t)(t - 3) * (2 * DI_DIM) + d]) * wd[0];
  if (t >= 2) acc += bf2f(xr[(size_t)(t - 2) * (2 * DI_DIM) + d]) * wd[1];
  if (t >= 1) acc += bf2f(xr[(size_t)(t - 1) * (2 * DI_DIM) + d]) * wd[2];
  acc += bf2f(xr[(size_t)t * (2 * DI_DIM) + d]) * wd[3];
  float s = acc / (1.f + __expf(-acc));
  xcb[idx] = f2bf(s);
}

__device__ __forceinline__ float softplusf(float p) {
  return (p > 20.f) ? p : log1pf(__expf(p));
}

// ---------------- scan phase A: per-chunk local scan ----------------
__global__ __launch_bounds__(256) void k_scan_a(
    const float* __restrict__ proj, const unsigned short* __restrict__ xcb,
    const float* __restrict__ A_log,
    float* __restrict__ Sdelta, float* __restrict__ hstate) {
  __shared__ float Bsh[LCHUNK * NSSM];
  const int d = blockIdx.x * 256 + threadIdx.x;
  const int c = blockIdx.y;
  const int t0 = c * LCHUNK;
  for (int i = threadIdx.x; i < LCHUNK * NSSM; i += 256) {
    int t = i >> 4, n = i & 15;
    Bsh[i] = proj[(size_t)(t0 + t) * NPROJ + DI_DIM + n];
  }
  __syncthreads();
  float Ar[NSSM], h[NSSM];
#pragma unroll
  for (int n = 0; n < NSSM; n++) {
    Ar[n] = -__expf(A_log[d * NSSM + n]);
    h[n] = 0.f;
  }
  float sd = 0.f;
  for (int t = 0; t < LCHUNK; t++) {
    int tt = t0 + t;
    float delta = softplusf(proj[(size_t)tt * NPROJ + d]);
    float xi = bf2f(xcb[(size_t)tt * DI_DIM + d]);
    float dx = delta * xi;
    sd += delta;
#pragma unroll
    for (int n = 0; n < NSSM; n++)
      h[n] = __expf(delta * Ar[n]) * h[n] + dx * Bsh[t * NSSM + n];
  }
  Sdelta[(size_t)c * DI_DIM + d] = sd;
#pragma unroll
  for (int n = 0; n < NSSM; n++)
    hstate[((size_t)c * DI_DIM + d) * NSSM + n] = h[n];
}

// ---------------- scan phase B: combine across chunks (in-place) ----------------
__global__ void k_scan_b(const float* __restrict__ A_log,
                         const float* __restrict__ Sdelta,
                         float* __restrict__ hstate) {
  int tid = blockIdx.x * 256 + threadIdx.x;  // d*16+n
  int d = tid >> 4;
  float A = -__expf(A_log[tid]);
  float carry = 0.f;
  for (int c = 0; c < NCHUNK; c++) {
    size_t idx = (size_t)c * DI_DIM * NSSM + tid;
    float v = hstate[idx];
    hstate[idx] = carry;
    carry = __expf(A * Sdelta[(size_t)c * DI_DIM + d]) * carry + v;
  }
}

// ---------------- scan phase C: replay with h0, produce y*silu(res) ----------------
__global__ __launch_bounds__(256) void k_scan_c(
    const float* __restrict__ proj, const unsigned short* __restrict__ xcb,
    const float* __restrict__ A_log, const float* __restrict__ h0,
    const float* __restrict__ Dvec, const unsigned short* __restrict__ xr,
    unsigned short* __restrict__ ybf) {
  __shared__ float Bsh[LCHUNK * NSSM];
  __shared__ float Csh[LCHUNK * NSSM];
  const int d = blockIdx.x * 256 + threadIdx.x;
  const int c = blockIdx.y;
  const int t0 = c * LCHUNK;
  for (int i = threadIdx.x; i < LCHUNK * NSSM; i += 256) {
    int t = i >> 4, n = i & 15;
    Bsh[i] = proj[(size_t)(t0 + t) * NPROJ + DI_DIM + n];
    Csh[i] = proj[(size_t)(t0 + t) * NPROJ + DI_DIM + NSSM + n];
  }
  __syncthreads();
  float Ar[NSSM], h[NSSM];
#pragma unroll
  for (int n = 0; n < NSSM; n++) {
    Ar[n] = -__expf(A_log[d * NSSM + n]);
    h[n] = h0[((size_t)c * DI_DIM + d) * NSSM + n];
  }
  float Dd = Dvec[d];
  for (int t = 0; t < LCHUNK; t++) {
    int tt = t0 + t;
    float delta = softplusf(proj[(size_t)tt * NPROJ + d]);
    float xi = bf2f(xcb[(size_t)tt * DI_DIM + d]);
    float dx = delta * xi;
    float y = 0.f;
#pragma unroll
    for (int n = 0; n < NSSM; n++) {
      h[n] = __expf(delta * Ar[n]) * h[n] + dx * Bsh[t * NSSM + n];
      y += h[n] * Csh[t * NSSM + n];
    }
    y += xi * Dd;
    float res = bf2f(xr[(size_t)tt * (2 * DI_DIM) + DI_DIM + d]);
    y *= res / (1.f + __expf(-res));
    ybf[(size_t)tt * DI_DIM + d] = f2bf(y);
  }
}

extern "C" void kernel_launch(void* const* d_in, const int* in_sizes, int n_in,
                              void* d_out, int out_size, void* d_ws, size_t ws_size,
                              hipStream_t stream) {
  const float* x      = (const float*)d_in[0];
  const float* W_in   = (const float*)d_in[1];
  const float* b_in   = (const float*)d_in[2];
  const float* W_conv = (const float*)d_in[3];
  const float* b_conv = (const float*)d_in[4];
  const float* W_x    = (const float*)d_in[5];
  const float* b_x    = (const float*)d_in[6];
  const float* W_out  = (const float*)d_in[7];
  const float* b_out  = (const float*)d_in[8];
  const float* A_log  = (const float*)d_in[9];
  const float* Dv     = (const float*)d_in[10];
  float* out = (float*)d_out;

  char* ws = (char*)d_ws;
  size_t off = 0;
  auto alloc = [&](size_t bytes) { void* p = ws + off; off += (bytes + 255) & ~(size_t)255; return p; };
  unsigned short* win_bf = (unsigned short*)alloc((size_t)4096 * DMODEL * 2);        // 8.39 MB; reused as ybf
  unsigned short* wx_bf  = (unsigned short*)alloc((size_t)NPROJ * DI_DIM * 2);       // 8.52 MB
  unsigned short* x_bf   = (unsigned short*)alloc((size_t)L_SEQ * DMODEL * 2);       // 4.19 MB; reused as wout_bf
  unsigned short* xr_bf  = (unsigned short*)alloc((size_t)L_SEQ * 2 * DI_DIM * 2);   // 16.78 MB
  unsigned short* xcb    = (unsigned short*)alloc((size_t)L_SEQ * DI_DIM * 2);       // 8.39 MB
  float* proj            = (float*)alloc((size_t)L_SEQ * NPROJ * 4);                 // 17.04 MB
  float* Sdelta          = (float*)alloc((size_t)NCHUNK * DI_DIM * 4);               // 0.52 MB
  float* hstate          = (float*)alloc((size_t)NCHUNK * DI_DIM * NSSM * 4);        // 8.39 MB
  if (off > ws_size) return;  // proven budget: 72.2 MB (same as round 4)
  unsigned short* ybf     = win_bf;  // dead after GEMM1, reborn as y (scan_c -> GEMM3)
  unsigned short* wout_bf = x_bf;    // dead after GEMM1, reborn as W_out bf16

  // zero-init split-K atomic targets (stream-ordered, graph-capture-safe)
  hipMemsetAsync(proj, 0, (size_t)L_SEQ * NPROJ * 4, stream);
  hipMemsetAsync(out, 0, (size_t)L_SEQ * DMODEL * 4, stream);

  // fused converts: x, W_in, W_x
  k_convert3<<<CVT_N3 / 256, 256, 0, stream>>>(x, W_in, W_x, x_bf, win_bf, wx_bf);

  // GEMM1: xr = x @ W_in^T + b_in (2048x4096, K=1024), bf16 out, unsplit (512 blocks)
  {
    dim3 g(4096 / 128, L_SEQ / 128, 1);
    k_gemm_bt<unsigned short, false><<<g, 256, 0, stream>>>(x_bf, win_bf, b_in, xr_bf, L_SEQ, 4096, DMODEL);
  }
  // convert W_out into x_bf's slot (x dead after GEMM1)
  k_f32_to_bf16<<<(DMODEL * DI_DIM / 4) / 256, 256, 0, stream>>>(W_out, wout_bf, DMODEL * DI_DIM / 4);
  // depthwise conv + SiLU
  k_conv_silu<<<(L_SEQ * DI_DIM) / 256, 256, 0, stream>>>(xr_bf, W_conv, b_conv, xcb);
  // GEMM2: proj += xi @ W_x^T + b_x (2048x2080, K=2048), split-K=4 -> 1088 blocks
  {
    dim3 g((NPROJ + 127) / 128, L_SEQ / 128, 4);
    k_gemm_bt<float, true><<<g, 256, 0, stream>>>(xcb, wx_bf, b_x, proj, L_SEQ, NPROJ, DI_DIM);
  }
  // selective scan (chunked 3-phase)
  {
    dim3 ga(DI_DIM / 256, NCHUNK);
    k_scan_a<<<ga, 256, 0, stream>>>(proj, xcb, A_log, Sdelta, hstate);
    k_scan_b<<<(DI_DIM * NSSM) / 256, 256, 0, stream>>>(A_log, Sdelta, hstate);
    k_scan_c<<<ga, 256, 0, stream>>>(proj, xcb, A_log, hstate, Dv, xr_bf, ybf);
  }
  // GEMM3: out += y @ W_out^T + b_out (2048x1024, K=2048), split-K=4 -> 512 blocks
  {
    dim3 g(DMODEL / 128, L_SEQ / 128, 4);
    k_gemm_bt<float, true><<<g, 256, 0, stream>>>(ybf, wout_bf, b_out, out, L_SEQ, DMODEL, DI_DIM);
  }
}

// Round 6
// 342.583 us; speedup vs baseline: 1.1119x; 1.1119x over previous
//
#include <hip/hip_runtime.h>
#include <stdint.h>

// Problem constants (B=1)
#define L_SEQ 2048
#define DMODEL 1024
#define DI_DIM 2048
#define NSSM 16
#define NPROJ 2080        // DI + 2N
#define NCHUNK 64
#define LCHUNK 32         // NCHUNK*LCHUNK == L_SEQ

typedef __attribute__((ext_vector_type(8))) short bf16x8;
typedef __attribute__((ext_vector_type(4))) float f32x4;

__device__ __forceinline__ float bf2f(unsigned short u) {
  union { uint32_t u; float f; } v; v.u = (uint32_t)u << 16; return v.f;
}
__device__ __forceinline__ unsigned short f2bf(float f) {
  union { float f; uint32_t u; } v; v.f = f;
  uint32_t u = v.u;
  return (unsigned short)((u + 0x7fffu + ((u >> 16) & 1u)) >> 16);
}
__device__ __forceinline__ void async16(const void* g, void* l) {
  __builtin_amdgcn_global_load_lds(
      (__attribute__((address_space(1))) void*)(g),
      (__attribute__((address_space(3))) void*)(l), 16, 0, 0);
}

// ---------------- fused f32 -> bf16 converts (x, W_in, W_x) ----------------
#define CVT_N1 524288                    // x:    2048*1024/4
#define CVT_N2 (CVT_N1 + 1048576)        // W_in: 4096*1024/4
#define CVT_N3 (CVT_N2 + 1064960)        // W_x:  2080*2048/4
__global__ void k_convert3(const float* __restrict__ x, const float* __restrict__ win,
                           const float* __restrict__ wx, unsigned short* __restrict__ xb,
                           unsigned short* __restrict__ winb, unsigned short* __restrict__ wxb) {
  int i = blockIdx.x * 256 + threadIdx.x;
  const float4* src; unsigned short* dst; int j;
  if (i < CVT_N1)      { src = (const float4*)x;   dst = xb;   j = i; }
  else if (i < CVT_N2) { src = (const float4*)win; dst = winb; j = i - CVT_N1; }
  else if (i < CVT_N3) { src = (const float4*)wx;  dst = wxb;  j = i - CVT_N2; }
  else return;
  float4 v = src[j];
  ushort4 o;
  o.x = f2bf(v.x); o.y = f2bf(v.y); o.z = f2bf(v.z); o.w = f2bf(v.w);
  ((ushort4*)dst)[j] = o;
}

__global__ void k_f32_to_bf16(const float* __restrict__ in,
                              unsigned short* __restrict__ out, int n4) {
  int i = blockIdx.x * blockDim.x + threadIdx.x;
  if (i < n4) {
    const float4 v = ((const float4*)in)[i];
    ushort4 o;
    o.x = f2bf(v.x); o.y = f2bf(v.y); o.z = f2bf(v.z); o.w = f2bf(v.w);
    ((ushort4*)out)[i] = o;
  }
}

// ---------------- bf16 N-T GEMM: C[M,N] = A[M,K] * B[N,K]^T + bias ----------------
// 128x128 tile, BK=32, 4 waves x (4x4) 16x16x32 MFMA.
// Double-buffered LDS + one barrier per K-iter: prefetch for tile k+1 is issued
// right after the barrier and has the whole compute phase to land before its
// drain at the next barrier (critical at ~1 block/CU where no other block hides it).
template <typename OutT>
__global__ __launch_bounds__(256) void k_gemm_bt(
    const unsigned short* __restrict__ A, const unsigned short* __restrict__ B,
    const float* __restrict__ bias, OutT* __restrict__ C,
    int M, int N, int K) {
  __shared__ unsigned short As[2][128 * 32];
  __shared__ unsigned short Bs[2][128 * 32];
  const int tid = threadIdx.x;
  const int wave = tid >> 6;
  const int lane = tid & 63;
  const int m0 = blockIdx.y * 128;
  const int n0 = blockIdx.x * 128;

  // staging: each wave issues 2 A + 2 B global_load_lds (16B/lane, 16 rows/instr)
  const int srow = wave * 32 + (lane >> 2);
  const int scol = (lane & 3) * 8;
  int ar0 = m0 + srow;      if (ar0 > M - 1) ar0 = M - 1;
  int ar1 = m0 + srow + 16; if (ar1 > M - 1) ar1 = M - 1;
  int br0 = n0 + srow;      if (br0 > N - 1) br0 = N - 1;
  int br1 = n0 + srow + 16; if (br1 > N - 1) br1 = N - 1;
  const unsigned short* ap0 = A + (size_t)ar0 * K + scol;
  const unsigned short* ap1 = A + (size_t)ar1 * K + scol;
  const unsigned short* bp0 = B + (size_t)br0 * K + scol;
  const unsigned short* bp1 = B + (size_t)br1 * K + scol;
  const int so0 = (wave * 32) * 32;
  const int so1 = (wave * 32 + 16) * 32;

  const int wm = wave & 1;
  const int wn = wave >> 1;
  const int fr = lane & 15;
  const int fk = (lane >> 4) * 8;

  f32x4 acc[4][4];
#pragma unroll
  for (int i = 0; i < 4; i++)
#pragma unroll
    for (int j = 0; j < 4; j++) acc[i][j] = (f32x4){0.f, 0.f, 0.f, 0.f};

  const int niter = K / 32;   // even for all our K

  // prologue: stage tile 0 into buffer 0
  async16(ap0, &As[0][so0]);
  async16(ap1, &As[0][so1]);
  async16(bp0, &Bs[0][so0]);
  async16(bp1, &Bs[0][so1]);

#define GEMM_COMPUTE(BUF)                                                      \
  {                                                                            \
    bf16x8 af[4], bfv[4];                                                      \
    _Pragma("unroll")                                                          \
    for (int i = 0; i < 4; i++)                                                \
      af[i] = *(const bf16x8*)&As[BUF][(wm * 64 + i * 16 + fr) * 32 + fk];     \
    _Pragma("unroll")                                                          \
    for (int j = 0; j < 4; j++)                                                \
      bfv[j] = *(const bf16x8*)&Bs[BUF][(wn * 64 + j * 16 + fr) * 32 + fk];    \
    _Pragma("unroll")                                                          \
    for (int i = 0; i < 4; i++)                                                \
      _Pragma("unroll")                                                        \
      for (int j = 0; j < 4; j++)                                              \
        acc[i][j] = __builtin_amdgcn_mfma_f32_16x16x32_bf16(af[i], bfv[j],     \
                                                            acc[i][j], 0, 0, 0); \
  }

  for (int it = 0; it < niter; it += 2) {
    __syncthreads();                       // drains own stage of buf0 (tile it)
    {                                      // prefetch tile it+1 -> buf1 (always valid: niter even)
      int kt = (it + 1) * 32;
      async16(ap0 + kt, &As[1][so0]);
      async16(ap1 + kt, &As[1][so1]);
      async16(bp0 + kt, &Bs[1][so0]);
      async16(bp1 + kt, &Bs[1][so1]);
    }
    GEMM_COMPUTE(0)
    __syncthreads();                       // drains stage of buf1; all waves done reading buf0
    if (it + 2 < niter) {                  // prefetch tile it+2 -> buf0
      int kt = (it + 2) * 32;
      async16(ap0 + kt, &As[0][so0]);
      async16(ap1 + kt, &As[0][so1]);
      async16(bp0 + kt, &Bs[0][so0]);
      async16(bp1 + kt, &Bs[0][so1]);
    }
    GEMM_COMPUTE(1)
  }
#undef GEMM_COMPUTE

  // epilogue: C/D layout col=lane&15, row=(lane>>4)*4+reg (verified mapping)
#pragma unroll
  for (int j = 0; j < 4; j++) {
    int col = n0 + wn * 64 + j * 16 + fr;
    if (col < N) {
      float bv = bias[col];
#pragma unroll
      for (int i = 0; i < 4; i++) {
        int rbase = m0 + wm * 64 + i * 16 + (lane >> 4) * 4;
#pragma unroll
        for (int r = 0; r < 4; r++) {
          float v = acc[i][j][r] + bv;
          if constexpr (sizeof(OutT) == 2)
            C[(size_t)(rbase + r) * N + col] = (OutT)f2bf(v);
          else
            C[(size_t)(rbase + r) * N + col] = (OutT)v;
        }
      }
    }
  }
}

// ---------------- depthwise causal conv (K=4) + bias + SiLU ----------------
__global__ void k_conv_silu(const unsigned short* __restrict__ xr,
                            const float* __restrict__ Wc,
                            const float* __restrict__ bc,
                            unsigned short* __restrict__ xcb) {
  int idx = blockIdx.x * blockDim.x + threadIdx.x;
  if (idx >= L_SEQ * DI_DIM) return;
  int t = idx >> 11;
  int d = idx & (DI_DIM - 1);
  float acc = bc[d];
  const float* wd = Wc + d * 4;
  if (t >= 3) acc += bf2f(xr[(size_t)(t - 3) * (2 * DI_DIM) + d]) * wd[0];
  if (t >= 2) acc += bf2f(xr[(size_t)(t - 2) * (2 * DI_DIM) + d]) * wd[1];
  if (t >= 1) acc += bf2f(xr[(size_t)(t - 1) * (2 * DI_DIM) + d]) * wd[2];
  acc += bf2f(xr[(size_t)t * (2 * DI_DIM) + d]) * wd[3];
  float s = acc / (1.f + __expf(-acc));
  xcb[idx] = f2bf(s);
}

__device__ __forceinline__ float softplusf(float p) {
  return (p > 20.f) ? p : log1pf(__expf(p));
}

// ---------------- scan phase A: per-chunk local scan ----------------
__global__ __launch_bounds__(256) void k_scan_a(
    const float* __restrict__ proj, const unsigned short* __restrict__ xcb,
    const float* __restrict__ A_log,
    float* __restrict__ Sdelta, float* __restrict__ hstate) {
  __shared__ float Bsh[LCHUNK * NSSM];
  const int d = blockIdx.x * 256 + threadIdx.x;
  const int c = blockIdx.y;
  const int t0 = c * LCHUNK;
  for (int i = threadIdx.x; i < LCHUNK * NSSM; i += 256) {
    int t = i >> 4, n = i & 15;
    Bsh[i] = proj[(size_t)(t0 + t) * NPROJ + DI_DIM + n];
  }
  __syncthreads();
  float Ar[NSSM], h[NSSM];
#pragma unroll
  for (int n = 0; n < NSSM; n++) {
    Ar[n] = -__expf(A_log[d * NSSM + n]);
    h[n] = 0.f;
  }
  float sd = 0.f;
  for (int t = 0; t < LCHUNK; t++) {
    int tt = t0 + t;
    float delta = softplusf(proj[(size_t)tt * NPROJ + d]);
    float xi = bf2f(xcb[(size_t)tt * DI_DIM + d]);
    float dx = delta * xi;
    sd += delta;
#pragma unroll
    for (int n = 0; n < NSSM; n++)
      h[n] = __expf(delta * Ar[n]) * h[n] + dx * Bsh[t * NSSM + n];
  }
  Sdelta[(size_t)c * DI_DIM + d] = sd;
#pragma unroll
  for (int n = 0; n < NSSM; n++)
    hstate[((size_t)c * DI_DIM + d) * NSSM + n] = h[n];
}

// ---------------- scan phase B: combine across chunks (in-place) ----------------
__global__ void k_scan_b(const float* __restrict__ A_log,
                         const float* __restrict__ Sdelta,
                         float* __restrict__ hstate) {
  int tid = blockIdx.x * 256 + threadIdx.x;  // d*16+n
  int d = tid >> 4;
  float A = -__expf(A_log[tid]);
  float carry = 0.f;
  for (int c = 0; c < NCHUNK; c++) {
    size_t idx = (size_t)c * DI_DIM * NSSM + tid;
    float v = hstate[idx];
    hstate[idx] = carry;
    carry = __expf(A * Sdelta[(size_t)c * DI_DIM + d]) * carry + v;
  }
}

// ---------------- scan phase C: replay with h0, produce y*silu(res) ----------------
__global__ __launch_bounds__(256) void k_scan_c(
    const float* __restrict__ proj, const unsigned short* __restrict__ xcb,
    const float* __restrict__ A_log, const float* __restrict__ h0,
    const float* __restrict__ Dvec, const unsigned short* __restrict__ xr,
    unsigned short* __restrict__ ybf) {
  __shared__ float Bsh[LCHUNK * NSSM];
  __shared__ float Csh[LCHUNK * NSSM];
  const int d = blockIdx.x * 256 + threadIdx.x;
  const int c = blockIdx.y;
  const int t0 = c * LCHUNK;
  for (int i = threadIdx.x; i < LCHUNK * NSSM; i += 256) {
    int t = i >> 4, n = i & 15;
    Bsh[i] = proj[(size_t)(t0 + t) * NPROJ + DI_DIM + n];
    Csh[i] = proj[(size_t)(t0 + t) * NPROJ + DI_DIM + NSSM + n];
  }
  __syncthreads();
  float Ar[NSSM], h[NSSM];
#pragma unroll
  for (int n = 0; n < NSSM; n++) {
    Ar[n] = -__expf(A_log[d * NSSM + n]);
    h[n] = h0[((size_t)c * DI_DIM + d) * NSSM + n];
  }
  float Dd = Dvec[d];
  for (int t = 0; t < LCHUNK; t++) {
    int tt = t0 + t;
    float delta = softplusf(proj[(size_t)tt * NPROJ + d]);
    float xi = bf2f(xcb[(size_t)tt * DI_DIM + d]);
    float dx = delta * xi;
    float y = 0.f;
#pragma unroll
    for (int n = 0; n < NSSM; n++) {
      h[n] = __expf(delta * Ar[n]) * h[n] + dx * Bsh[t * NSSM + n];
      y += h[n] * Csh[t * NSSM + n];
    }
    y += xi * Dd;
    float res = bf2f(xr[(size_t)tt * (2 * DI_DIM) + DI_DIM + d]);
    y *= res / (1.f + __expf(-res));
    ybf[(size_t)tt * DI_DIM + d] = f2bf(y);
  }
}

extern "C" void kernel_launch(void* const* d_in, const int* in_sizes, int n_in,
                              void* d_out, int out_size, void* d_ws, size_t ws_size,
                              hipStream_t stream) {
  const float* x      = (const float*)d_in[0];
  const float* W_in   = (const float*)d_in[1];
  const float* b_in   = (const float*)d_in[2];
  const float* W_conv = (const float*)d_in[3];
  const float* b_conv = (const float*)d_in[4];
  const float* W_x    = (const float*)d_in[5];
  const float* b_x    = (const float*)d_in[6];
  const float* W_out  = (const float*)d_in[7];
  const float* b_out  = (const float*)d_in[8];
  const float* A_log  = (const float*)d_in[9];
  const float* Dv     = (const float*)d_in[10];
  float* out = (float*)d_out;

  char* ws = (char*)d_ws;
  size_t off = 0;
  auto alloc = [&](size_t bytes) { void* p = ws + off; off += (bytes + 255) & ~(size_t)255; return p; };
  unsigned short* win_bf = (unsigned short*)alloc((size_t)4096 * DMODEL * 2);        // 8.39 MB; reused as ybf
  unsigned short* wx_bf  = (unsigned short*)alloc((size_t)NPROJ * DI_DIM * 2);       // 8.52 MB
  unsigned short* x_bf   = (unsigned short*)alloc((size_t)L_SEQ * DMODEL * 2);       // 4.19 MB; reused as wout_bf
  unsigned short* xr_bf  = (unsigned short*)alloc((size_t)L_SEQ * 2 * DI_DIM * 2);   // 16.78 MB
  unsigned short* xcb    = (unsigned short*)alloc((size_t)L_SEQ * DI_DIM * 2);       // 8.39 MB
  float* proj            = (float*)alloc((size_t)L_SEQ * NPROJ * 4);                 // 17.04 MB
  float* Sdelta          = (float*)alloc((size_t)NCHUNK * DI_DIM * 4);               // 0.52 MB
  float* hstate          = (float*)alloc((size_t)NCHUNK * DI_DIM * NSSM * 4);        // 8.39 MB
  if (off > ws_size) return;  // proven budget: 72.2 MB
  unsigned short* ybf     = win_bf;  // dead after GEMM1, reborn as y (scan_c -> GEMM3)
  unsigned short* wout_bf = x_bf;    // dead after GEMM1, reborn as W_out bf16

  // fused converts: x, W_in, W_x
  k_convert3<<<CVT_N3 / 256, 256, 0, stream>>>(x, W_in, W_x, x_bf, win_bf, wx_bf);

  // GEMM1: xr = x @ W_in^T + b_in (2048x4096, K=1024), bf16 out (512 blocks)
  {
    dim3 g(4096 / 128, L_SEQ / 128);
    k_gemm_bt<unsigned short><<<g, 256, 0, stream>>>(x_bf, win_bf, b_in, xr_bf, L_SEQ, 4096, DMODEL);
  }
  // convert W_out into x_bf's slot (x dead after GEMM1)
  k_f32_to_bf16<<<(DMODEL * DI_DIM / 4) / 256, 256, 0, stream>>>(W_out, wout_bf, DMODEL * DI_DIM / 4);
  // depthwise conv + SiLU
  k_conv_silu<<<(L_SEQ * DI_DIM) / 256, 256, 0, stream>>>(xr_bf, W_conv, b_conv, xcb);
  // GEMM2: proj = xi @ W_x^T + b_x (2048x2080, K=2048), f32 out (272 blocks)
  {
    dim3 g((NPROJ + 127) / 128, L_SEQ / 128);
    k_gemm_bt<float><<<g, 256, 0, stream>>>(xcb, wx_bf, b_x, proj, L_SEQ, NPROJ, DI_DIM);
  }
  // selective scan (chunked 3-phase)
  {
    dim3 ga(DI_DIM / 256, NCHUNK);
    k_scan_a<<<ga, 256, 0, stream>>>(proj, xcb, A_log, Sdelta, hstate);
    k_scan_b<<<(DI_DIM * NSSM) / 256, 256, 0, stream>>>(A_log, Sdelta, hstate);
    k_scan_c<<<ga, 256, 0, stream>>>(proj, xcb, A_log, hstate, Dv, xr_bf, ybf);
  }
  // GEMM3: out = y @ W_out^T + b_out (2048x1024, K=2048), f32 out (128 blocks)
  {
    dim3 g(DMODEL / 128, L_SEQ / 128);
    k_gemm_bt<float><<<g, 256, 0, stream>>>(ybf, wout_bf, b_out, out, L_SEQ, DMODEL, DI_DIM);
  }
}

// Round 7
// 280.974 us; speedup vs baseline: 1.3557x; 1.2193x over previous
//
#include <hip/hip_runtime.h>
#include <stdint.h>

// Problem constants (B=1)
#define L_SEQ 2048
#define DMODEL 1024
#define DI_DIM 2048
#define NSSM 16
#define NPROJ 2080        // DI + 2N
#define NCHUNK 64
#define LCHUNK 32         // NCHUNK*LCHUNK == L_SEQ

typedef __attribute__((ext_vector_type(8))) short bf16x8;
typedef __attribute__((ext_vector_type(4))) float f32x4;

__device__ __forceinline__ float bf2f(unsigned short u) {
  union { uint32_t u; float f; } v; v.u = (uint32_t)u << 16; return v.f;
}
__device__ __forceinline__ unsigned short f2bf(float f) {
  union { float f; uint32_t u; } v; v.f = f;
  uint32_t u = v.u;
  return (unsigned short)((u + 0x7fffu + ((u >> 16) & 1u)) >> 16);
}
__device__ __forceinline__ void async16(const void* g, void* l) {
  __builtin_amdgcn_global_load_lds(
      (__attribute__((address_space(1))) void*)(g),
      (__attribute__((address_space(3))) void*)(l), 16, 0, 0);
}
// native-op math (no libm: default compile is non-fast-math and log1pf/fdiv
// expand to huge sequences -- measured 4x VALU inflation in scan kernels)
__device__ __forceinline__ float softplusf(float p) {
  return (p > 20.f) ? p : __logf(1.f + __expf(p));
}
__device__ __forceinline__ float siluf(float x) {
  return x * __builtin_amdgcn_rcpf(1.f + __expf(-x));
}

// ---------------- fused f32 -> bf16 converts (x, W_in, W_x) ----------------
#define CVT_N1 524288                    // x:    2048*1024/4
#define CVT_N2 (CVT_N1 + 1048576)        // W_in: 4096*1024/4
#define CVT_N3 (CVT_N2 + 1064960)        // W_x:  2080*2048/4
__global__ void k_convert3(const float* __restrict__ x, const float* __restrict__ win,
                           const float* __restrict__ wx, unsigned short* __restrict__ xb,
                           unsigned short* __restrict__ winb, unsigned short* __restrict__ wxb) {
  int i = blockIdx.x * 256 + threadIdx.x;
  const float4* src; unsigned short* dst; int j;
  if (i < CVT_N1)      { src = (const float4*)x;   dst = xb;   j = i; }
  else if (i < CVT_N2) { src = (const float4*)win; dst = winb; j = i - CVT_N1; }
  else if (i < CVT_N3) { src = (const float4*)wx;  dst = wxb;  j = i - CVT_N2; }
  else return;
  float4 v = src[j];
  ushort4 o;
  o.x = f2bf(v.x); o.y = f2bf(v.y); o.z = f2bf(v.z); o.w = f2bf(v.w);
  ((ushort4*)dst)[j] = o;
}

__global__ void k_f32_to_bf16(const float* __restrict__ in,
                              unsigned short* __restrict__ out, int n4) {
  int i = blockIdx.x * blockDim.x + threadIdx.x;
  if (i < n4) {
    const float4 v = ((const float4*)in)[i];
    ushort4 o;
    o.x = f2bf(v.x); o.y = f2bf(v.y); o.z = f2bf(v.z); o.w = f2bf(v.w);
    ((ushort4*)out)[i] = o;
  }
}

// ---------------- bf16 N-T GEMM: C = A[M,K] * B[N,K]^T (+bias) ----------------
// 64x128 tile (more blocks -> cross-block latency overlap, the measured
// mechanism at grid-starved shapes), BK=32, 4 waves; wave w computes
// 64M x 32N via 4x2 of 16x16x32 MFMA. Double-buffered LDS (24 KB).
// gridDim.z>1: split-K, block z writes its partial to C + z*M*N, no bias.
template <typename OutT>
__global__ __launch_bounds__(256) void k_gemm_bt(
    const unsigned short* __restrict__ A, const unsigned short* __restrict__ B,
    const float* __restrict__ bias, OutT* __restrict__ C,
    int M, int N, int K) {
  __shared__ unsigned short As[2][64 * 32];
  __shared__ unsigned short Bs[2][128 * 32];
  const int tid = threadIdx.x;
  const int wave = tid >> 6;
  const int lane = tid & 63;
  const int m0 = blockIdx.y * 64;
  const int n0 = blockIdx.x * 128;
  const int kLen = K / gridDim.z;
  const int kLo = blockIdx.z * kLen;

  // A staging: 1 instr/wave (16 rows); B staging: 2 instr/wave (32 rows)
  const int scol = (lane & 3) * 8;
  int ar = m0 + wave * 16 + (lane >> 2);       if (ar > M - 1) ar = M - 1;
  int br0 = n0 + wave * 32 + (lane >> 2);      if (br0 > N - 1) br0 = N - 1;
  int br1 = n0 + wave * 32 + 16 + (lane >> 2); if (br1 > N - 1) br1 = N - 1;
  const unsigned short* ap  = A + (size_t)ar * K + scol + kLo;
  const unsigned short* bp0 = B + (size_t)br0 * K + scol + kLo;
  const unsigned short* bp1 = B + (size_t)br1 * K + scol + kLo;
  const int soA  = (wave * 16) * 32;
  const int soB0 = (wave * 32) * 32;
  const int soB1 = (wave * 32 + 16) * 32;

  const int fr = lane & 15;
  const int fk = (lane >> 4) * 8;

  f32x4 acc[4][2];
#pragma unroll
  for (int i = 0; i < 4; i++)
#pragma unroll
    for (int j = 0; j < 2; j++) acc[i][j] = (f32x4){0.f, 0.f, 0.f, 0.f};

  const int niter = kLen / 32;   // >=32 and even for all our shapes

  // prologue: stage tile 0 into buffer 0
  async16(ap, &As[0][soA]);
  async16(bp0, &Bs[0][soB0]);
  async16(bp1, &Bs[0][soB1]);

#define GEMM_COMPUTE(BUF)                                                      \
  {                                                                            \
    bf16x8 af[4], bfv[2];                                                      \
    _Pragma("unroll")                                                          \
    for (int i = 0; i < 4; i++)                                                \
      af[i] = *(const bf16x8*)&As[BUF][(i * 16 + fr) * 32 + fk];               \
    _Pragma("unroll")                                                          \
    for (int j = 0; j < 2; j++)                                                \
      bfv[j] = *(const bf16x8*)&Bs[BUF][(wave * 32 + j * 16 + fr) * 32 + fk];  \
    _Pragma("unroll")                                                          \
    for (int i = 0; i < 4; i++)                                                \
      _Pragma("unroll")                                                        \
      for (int j = 0; j < 2; j++)                                              \
        acc[i][j] = __builtin_amdgcn_mfma_f32_16x16x32_bf16(af[i], bfv[j],     \
                                                            acc[i][j], 0, 0, 0); \
  }

  for (int it = 0; it < niter; it += 2) {
    __syncthreads();
    {
      int kt = (it + 1) * 32;
      async16(ap + kt, &As[1][soA]);
      async16(bp0 + kt, &Bs[1][soB0]);
      async16(bp1 + kt, &Bs[1][soB1]);
    }
    GEMM_COMPUTE(0)
    __syncthreads();
    if (it + 2 < niter) {
      int kt = (it + 2) * 32;
      async16(ap + kt, &As[0][soA]);
      async16(bp0 + kt, &Bs[0][soB0]);
      async16(bp1 + kt, &Bs[0][soB1]);
    }
    GEMM_COMPUTE(1)
  }
#undef GEMM_COMPUTE

  // epilogue: C/D layout col=lane&15, row=(lane>>4)*4+reg (verified mapping)
  const bool withBias = (gridDim.z == 1);
  OutT* Cz = C + (size_t)blockIdx.z * ((size_t)M * N);
#pragma unroll
  for (int j = 0; j < 2; j++) {
    int col = n0 + wave * 32 + j * 16 + fr;
    if (col < N) {
      float bv = withBias ? bias[col] : 0.f;
#pragma unroll
      for (int i = 0; i < 4; i++) {
        int rbase = m0 + i * 16 + (lane >> 4) * 4;
#pragma unroll
        for (int r = 0; r < 4; r++) {
          float v = acc[i][j][r] + bv;
          if constexpr (sizeof(OutT) == 2)
            Cz[(size_t)(rbase + r) * N + col] = (OutT)f2bf(v);
          else
            Cz[(size_t)(rbase + r) * N + col] = (OutT)v;
        }
      }
    }
  }
}

// ---------------- split-K reduce: out = p0 + p1 + bias ----------------
__global__ void k_reduce_out(const float* __restrict__ part, const float* __restrict__ bias,
                             float* __restrict__ out) {
  int i = blockIdx.x * 256 + threadIdx.x;   // float4 index over 2048*1024
  float4 a = ((const float4*)part)[i];
  float4 b = ((const float4*)(part + (size_t)L_SEQ * DMODEL))[i];
  int col = (i * 4) & (DMODEL - 1);
  float4 bb = *(const float4*)&bias[col];
  float4 o;
  o.x = a.x + b.x + bb.x; o.y = a.y + b.y + bb.y;
  o.z = a.z + b.z + bb.z; o.w = a.w + b.w + bb.w;
  ((float4*)out)[i] = o;
}

// ---------------- depthwise causal conv (K=4) + bias + SiLU ----------------
__global__ void k_conv_silu(const unsigned short* __restrict__ xr,
                            const float* __restrict__ Wc,
                            const float* __restrict__ bc,
                            unsigned short* __restrict__ xcb) {
  int idx = blockIdx.x * blockDim.x + threadIdx.x;
  if (idx >= L_SEQ * DI_DIM) return;
  int t = idx >> 11;
  int d = idx & (DI_DIM - 1);
  float acc = bc[d];
  const float* wd = Wc + d * 4;
  if (t >= 3) acc += bf2f(xr[(size_t)(t - 3) * (2 * DI_DIM) + d]) * wd[0];
  if (t >= 2) acc += bf2f(xr[(size_t)(t - 2) * (2 * DI_DIM) + d]) * wd[1];
  if (t >= 1) acc += bf2f(xr[(size_t)(t - 1) * (2 * DI_DIM) + d]) * wd[2];
  acc += bf2f(xr[(size_t)t * (2 * DI_DIM) + d]) * wd[3];
  xcb[idx] = f2bf(siluf(acc));
}

// ---------------- scan phase A: per-chunk local scan ----------------
__global__ __launch_bounds__(256) void k_scan_a(
    const float* __restrict__ proj, const unsigned short* __restrict__ xcb,
    const float* __restrict__ A_log,
    float* __restrict__ Sdelta, float* __restrict__ hstate) {
  __shared__ float Bsh[LCHUNK * NSSM];
  const int d = blockIdx.x * 256 + threadIdx.x;
  const int c = blockIdx.y;
  const int t0 = c * LCHUNK;
  for (int i = threadIdx.x; i < LCHUNK * NSSM; i += 256) {
    int t = i >> 4, n = i & 15;
    Bsh[i] = proj[(size_t)(t0 + t) * NPROJ + DI_DIM + n];
  }
  __syncthreads();
  float Ar[NSSM], h[NSSM];
#pragma unroll
  for (int n = 0; n < NSSM; n++) {
    Ar[n] = -__expf(A_log[d * NSSM + n]);
    h[n] = 0.f;
  }
  const float* pp = proj + (size_t)t0 * NPROJ + d;
  const unsigned short* xp = xcb + (size_t)t0 * DI_DIM + d;
  float p_nxt = pp[0];
  unsigned short x_nxt = xp[0];
  float sd = 0.f;
  for (int t = 0; t < LCHUNK; t++) {
    float p = p_nxt;
    unsigned short xu = x_nxt;
    if (t + 1 < LCHUNK) {                          // prefetch next step
      p_nxt = pp[(size_t)(t + 1) * NPROJ];
      x_nxt = xp[(size_t)(t + 1) * DI_DIM];
    }
    float delta = softplusf(p);
    float dx = delta * bf2f(xu);
    sd += delta;
#pragma unroll
    for (int n = 0; n < NSSM; n++)
      h[n] = __expf(delta * Ar[n]) * h[n] + dx * Bsh[t * NSSM + n];
  }
  Sdelta[(size_t)c * DI_DIM + d] = sd;
#pragma unroll
  for (int n = 0; n < NSSM; n++)
    hstate[((size_t)c * DI_DIM + d) * NSSM + n] = h[n];
}

// ---------------- scan phase B: combine across chunks (in-place) ----------------
__global__ void k_scan_b(const float* __restrict__ A_log,
                         const float* __restrict__ Sdelta,
                         float* __restrict__ hstate) {
  int tid = blockIdx.x * 256 + threadIdx.x;  // d*16+n
  int d = tid >> 4;
  float A = -__expf(A_log[tid]);
  float carry = 0.f;
  float v_nxt = hstate[tid];
  float s_nxt = Sdelta[d];
  for (int c = 0; c < NCHUNK; c++) {
    float v = v_nxt, s = s_nxt;
    if (c + 1 < NCHUNK) {                          // prefetch next chunk
      v_nxt = hstate[(size_t)(c + 1) * DI_DIM * NSSM + tid];
      s_nxt = Sdelta[(size_t)(c + 1) * DI_DIM + d];
    }
    hstate[(size_t)c * DI_DIM * NSSM + tid] = carry;
    carry = __expf(A * s) * carry + v;
  }
}

// ---------------- scan phase C: replay with h0, produce y*silu(res) ----------------
__global__ __launch_bounds__(256) void k_scan_c(
    const float* __restrict__ proj, const unsigned short* __restrict__ xcb,
    const float* __restrict__ A_log, const float* __restrict__ h0,
    const float* __restrict__ Dvec, const unsigned short* __restrict__ xr,
    unsigned short* __restrict__ ybf) {
  __shared__ float Bsh[LCHUNK * NSSM];
  __shared__ float Csh[LCHUNK * NSSM];
  const int d = blockIdx.x * 256 + threadIdx.x;
  const int c = blockIdx.y;
  const int t0 = c * LCHUNK;
  for (int i = threadIdx.x; i < LCHUNK * NSSM; i += 256) {
    int t = i >> 4, n = i & 15;
    Bsh[i] = proj[(size_t)(t0 + t) * NPROJ + DI_DIM + n];
    Csh[i] = proj[(size_t)(t0 + t) * NPROJ + DI_DIM + NSSM + n];
  }
  __syncthreads();
  float Ar[NSSM], h[NSSM];
#pragma unroll
  for (int n = 0; n < NSSM; n++) {
    Ar[n] = -__expf(A_log[d * NSSM + n]);
    h[n] = h0[((size_t)c * DI_DIM + d) * NSSM + n];
  }
  float Dd = Dvec[d];
  const float* pp = proj + (size_t)t0 * NPROJ + d;
  const unsigned short* xp = xcb + (size_t)t0 * DI_DIM + d;
  const unsigned short* rp = xr + (size_t)t0 * (2 * DI_DIM) + DI_DIM + d;
  float p_nxt = pp[0];
  unsigned short x_nxt = xp[0];
  unsigned short r_nxt = rp[0];
  for (int t = 0; t < LCHUNK; t++) {
    float p = p_nxt;
    unsigned short xu = x_nxt, ru = r_nxt;
    if (t + 1 < LCHUNK) {                          // prefetch next step
      p_nxt = pp[(size_t)(t + 1) * NPROJ];
      x_nxt = xp[(size_t)(t + 1) * DI_DIM];
      r_nxt = rp[(size_t)(t + 1) * (2 * DI_DIM)];
    }
    float delta = softplusf(p);
    float xi = bf2f(xu);
    float dx = delta * xi;
    float y = 0.f;
#pragma unroll
    for (int n = 0; n < NSSM; n++) {
      h[n] = __expf(delta * Ar[n]) * h[n] + dx * Bsh[t * NSSM + n];
      y += h[n] * Csh[t * NSSM + n];
    }
    y += xi * Dd;
    y *= siluf(bf2f(ru));
    ybf[(size_t)(t0 + t) * DI_DIM + d] = f2bf(y);
  }
}

extern "C" void kernel_launch(void* const* d_in, const int* in_sizes, int n_in,
                              void* d_out, int out_size, void* d_ws, size_t ws_size,
                              hipStream_t stream) {
  const float* x      = (const float*)d_in[0];
  const float* W_in   = (const float*)d_in[1];
  const float* b_in   = (const float*)d_in[2];
  const float* W_conv = (const float*)d_in[3];
  const float* b_conv = (const float*)d_in[4];
  const float* W_x    = (const float*)d_in[5];
  const float* b_x    = (const float*)d_in[6];
  const float* W_out  = (const float*)d_in[7];
  const float* b_out  = (const float*)d_in[8];
  const float* A_log  = (const float*)d_in[9];
  const float* Dv     = (const float*)d_in[10];
  float* out = (float*)d_out;

  char* ws = (char*)d_ws;
  size_t off = 0;
  auto alloc = [&](size_t bytes) { void* p = ws + off; off += (bytes + 255) & ~(size_t)255; return p; };
  unsigned short* win_bf = (unsigned short*)alloc((size_t)4096 * DMODEL * 2);        // 8.39 MB; reused as ybf
  unsigned short* wx_bf  = (unsigned short*)alloc((size_t)NPROJ * DI_DIM * 2);       // 8.52 MB
  unsigned short* x_bf   = (unsigned short*)alloc((size_t)L_SEQ * DMODEL * 2);       // 4.19 MB; reused as wout_bf
  unsigned short* xr_bf  = (unsigned short*)alloc((size_t)L_SEQ * 2 * DI_DIM * 2);   // 16.78 MB
  unsigned short* xcb    = (unsigned short*)alloc((size_t)L_SEQ * DI_DIM * 2);       // 8.39 MB
  float* proj            = (float*)alloc((size_t)L_SEQ * NPROJ * 4);                 // 17.04 MB; reused as GEMM3 partials
  float* Sdelta          = (float*)alloc((size_t)NCHUNK * DI_DIM * 4);               // 0.52 MB
  float* hstate          = (float*)alloc((size_t)NCHUNK * DI_DIM * NSSM * 4);        // 8.39 MB
  if (off > ws_size) return;  // proven budget: 72.2 MB
  unsigned short* ybf     = win_bf;  // dead after GEMM1, reborn as y (scan_c -> GEMM3)
  unsigned short* wout_bf = x_bf;    // dead after GEMM1, reborn as W_out bf16
  float* part             = proj;    // dead after scan_c, reborn as GEMM3 split-K partials (2 x 8.39 MB)

  // fused converts: x, W_in, W_x
  k_convert3<<<CVT_N3 / 256, 256, 0, stream>>>(x, W_in, W_x, x_bf, win_bf, wx_bf);

  // GEMM1: xr = x @ W_in^T + b_in (2048x4096, K=1024), bf16 out, 1024 blocks
  {
    dim3 g(4096 / 128, L_SEQ / 64);
    k_gemm_bt<unsigned short><<<g, 256, 0, stream>>>(x_bf, win_bf, b_in, xr_bf, L_SEQ, 4096, DMODEL);
  }
  // convert W_out into x_bf's slot (x dead after GEMM1)
  k_f32_to_bf16<<<(DMODEL * DI_DIM / 4) / 256, 256, 0, stream>>>(W_out, wout_bf, DMODEL * DI_DIM / 4);
  // depthwise conv + SiLU
  k_conv_silu<<<(L_SEQ * DI_DIM) / 256, 256, 0, stream>>>(xr_bf, W_conv, b_conv, xcb);
  // GEMM2: proj = xi @ W_x^T + b_x (2048x2080, K=2048), f32 out, 544 blocks
  {
    dim3 g((NPROJ + 127) / 128, L_SEQ / 64);
    k_gemm_bt<float><<<g, 256, 0, stream>>>(xcb, wx_bf, b_x, proj, L_SEQ, NPROJ, DI_DIM);
  }
  // selective scan (chunked 3-phase)
  {
    dim3 ga(DI_DIM / 256, NCHUNK);
    k_scan_a<<<ga, 256, 0, stream>>>(proj, xcb, A_log, Sdelta, hstate);
    k_scan_b<<<(DI_DIM * NSSM) / 256, 256, 0, stream>>>(A_log, Sdelta, hstate);
    k_scan_c<<<ga, 256, 0, stream>>>(proj, xcb, A_log, hstate, Dv, xr_bf, ybf);
  }
  // GEMM3: split-K=2 partials (2048x1024, K=1024 each), 512 blocks, then reduce+bias
  {
    dim3 g(DMODEL / 128, L_SEQ / 64, 2);
    k_gemm_bt<float><<<g, 256, 0, stream>>>(ybf, wout_bf, b_out, part, L_SEQ, DMODEL, DI_DIM);
    k_reduce_out<<<(L_SEQ * DMODEL / 4) / 256, 256, 0, stream>>>(part, b_out, out);
  }
}